// Round 6
// baseline (932.519 us; speedup 1.0000x reference)
//
#include <hip/hip_runtime.h>
#include <hip/hip_cooperative_groups.h>
#include <math.h>

namespace cg = cooperative_groups;

#define B_ 64
#define N_ 512
#define R_ (B_*N_)                  // 32768 rows
#define INV_S 0.9995003746877732f   // 1/sqrt(1+1e-3)

struct FusedArgs {
  const float* xx;
  const float* emb1; const float* emb2; const float* emb3;
  const float* A0;  const float* b0;
  const float* Ar;  const float* br;
  const float* bng; const float* bnb;
  const float* dW0; const float* db0;
  const float* dW1; const float* db1;
  const float* dbg; const float* dbb;
  const float* W2;  const float* b2;
  float* xA; float* xB; float* partial;
  float* out;
};

// ---------------------------------------------------------------------------
// Single cooperative kernel, grid-size agnostic (grid-stride everywhere).
// LDS ~28.4 KB/block => co-residency validator (64 KB pool) gives 2
// blocks/CU => 512 blocks OK, 8 waves/CU (round 5 at 61 KB got 1/CU => 12%
// occupancy and 533 us of exposed latency).
// A matrices are NOT staged in LDS: they are <=33 KB, L1/L2-resident, read
// as global float4 fragments inside the k-loop (kills the branchy A-staging
// phase that serialized round 5).
//  Per layer L=0..4 (tile = 64 rows):
//   - stage coords (512 x float4) + x tile (64x68) + mask
//   - S/T: 4 waves x 128-i ranges -> spart/tpart -> scl/tcl
//   - GEMM: thread = 4 rows x 4 outs x 2 mats; per 4-k chunk 8 global A
//     loads + 4 LDS x loads + 128 FMA. L0: 8 chunks (k<32) + k=32 remainder.
//   - epilogue (alast/bias/mask/bn/tanh) -> ping-pong; grid.sync
//  Dense0: grid-stride over 512 k-chunks of 64 -> partial; grid.sync
//  Head (blocks 0..63): reduce 512 partials -> bn+sigmoid -> 128x128 GEMV
//  -> bn+sigmoid -> @W2+b2 -> out (B,4).
// ---------------------------------------------------------------------------
__global__ __launch_bounds__(256, 4) void gnn_fused(FusedArgs a)
{
  __shared__ union {
    struct {
      float4 cl[512];            // 8192 B
      float xl[64*68];           // 17408 B
      float spart[256], tpart[256];  // 2048 B
    } lay;                       // 27648 B
    struct {
      float xt[64*36];           // 9216 B
      float wt[32*128];          // 16384 B
    } den;                       // 25600 B
    struct {
      float sred[256]; float h[128]; float red0[128]; float red1[128];
    } head;
  } u;
  __shared__ float scl[64], tcl[64], ml[64];

  cg::grid_group grid = cg::this_grid();
  int tid = threadIdx.x;
  int bid = blockIdx.x;
  int gsz = gridDim.x;

  // ======================== GNN layers ========================
  for (int L = 0; L < 5; L++){
    const float* A    = (L==0) ? a.A0 : (a.Ar + (size_t)(L-1)*129*64);
    const float* bias = (L==0) ? a.b0 : (a.br + (L-1)*64);
    const float* gam  = a.bng + L*64;
    const float* bet  = a.bnb + L*64;
    int K = (L==0) ? 33 : 64;
    const float* Ahi   = A + (size_t)K*64;
    const float* Alast = A + (size_t)2*K*64;
    const float* xin  = (L&1) ? a.xA : a.xB;   // valid for L>=1
    float* xout       = (L&1) ? a.xB : a.xA;

    for (int t = bid; t < 512; t += gsz){
      int b = t >> 3, jc = t & 7;
      int rbase = b*N_, jloc = jc*64;
      __syncthreads();   // previous iteration's LDS reads complete

      // ---- stage coords for all 512 rows of this batch ----
      if (L == 0){
        for (int i = tid; i < 512; i += 256){
          const float* row = a.xx + (size_t)(rbase+i)*30;
          u.lay.cl[i] = make_float4(row[25], row[26], 0.f, 0.f);
        }
      } else {
        for (int i = tid; i < 512; i += 256)
          u.lay.cl[i] = *(const float4*)&xin[(size_t)(rbase+i)*64 + 60];
      }

      // ---- stage x tile (64 rows, stride 68) + mask ----
      if (L == 0){
        if (tid < 64){
          int r = rbase + jloc + tid;
          const float* row = a.xx + (size_t)r*30;
          float v[30];
#pragma unroll
          for (int i=0;i<30;i++) v[i] = row[i];
          int i1 = (int)fabsf(v[27]);
          int i2 = (int)fabsf(v[28]);
          int i3 = (int)fabsf(v[29]);
          float* o = &u.lay.xl[tid*68];
          o[0]=a.emb1[i1*2+0]; o[1]=a.emb1[i1*2+1];
          o[2]=a.emb2[i2*2+0]; o[3]=a.emb2[i2*2+1];
          o[4]=a.emb3[i3*2+0]; o[5]=a.emb3[i3*2+1];
#pragma unroll
          for (int i=0;i<27;i++) o[6+i] = v[i];
          ml[tid] = v[0];
        }
      } else {
        for (int idx = tid; idx < 1024; idx += 256){
          int jj = idx >> 4, fq = idx & 15;
          *(float4*)&u.lay.xl[jj*68 + fq*4] =
              *(const float4*)&xin[(size_t)(rbase+jloc+jj)*64 + fq*4];
        }
        if (tid < 64) ml[tid] = a.xx[(size_t)(rbase+jloc+tid)*30];
      }
      __syncthreads();

      // ---- S,T: wave q sums i in [q*128, q*128+128) for j = tid&63 ----
      {
        int jj = tid & 63, q = tid >> 6;
        float4 cj = u.lay.cl[jloc + jj];
        float Ss = 0.f, Ts = 0.f;
        int base = q*128;
#pragma unroll 8
        for (int i=0;i<128;i++){
          float4 ci = u.lay.cl[base+i];
          float d0 = cj.x-ci.x, d1 = cj.y-ci.y, d2 = cj.z-ci.z, d3 = cj.w-ci.w;
          float dist = d0*d0 + d1*d1 + d2*d2 + d3*d3;
          float w = __expf(-10.f*dist);
          Ss += w;
          Ts += dist*w;
        }
        u.lay.spart[tid] = Ss;
        u.lay.tpart[tid] = Ts;
      }
      __syncthreads();
      if (tid < 64){
        float S = u.lay.spart[tid] + u.lay.spart[tid+64]
                + u.lay.spart[tid+128] + u.lay.spart[tid+192];
        float T = u.lay.tpart[tid] + u.lay.tpart[tid+64]
                + u.lay.tpart[tid+128] + u.lay.tpart[tid+192];
        float m = ml[tid];
        scl[tid] = m*S - 1.f;
        tcl[tid] = m*T;
      }
      __syncthreads();

      // ---- GEMM: A fragments from global (L1/L2-resident) ----
      int o0 = (tid & 15)*4, r0 = (tid >> 4)*4;
      float4 acc1[4], acc2[4];
#pragma unroll
      for (int rr=0;rr<4;rr++){
        acc1[rr] = make_float4(0.f,0.f,0.f,0.f);
        acc2[rr] = make_float4(0.f,0.f,0.f,0.f);
      }
      int nck = (L==0) ? 8 : 16;   // L0: k<32 here, k=32 remainder below
#pragma unroll 1
      for (int c = 0; c < nck; c++){
        int kc = c*4;
        float4 a1[4], a2[4], xv[4];
#pragma unroll
        for (int uu=0;uu<4;uu++){
          a1[uu] = *(const float4*)&A  [(size_t)(kc+uu)*64 + o0];
          a2[uu] = *(const float4*)&Ahi[(size_t)(kc+uu)*64 + o0];
        }
#pragma unroll
        for (int rr=0;rr<4;rr++)
          xv[rr] = *(const float4*)&u.lay.xl[(r0+rr)*68 + kc];
#pragma unroll
        for (int uu=0;uu<4;uu++){
#pragma unroll
          for (int rr=0;rr<4;rr++){
            float xu = ((const float*)&xv[rr])[uu];
            acc1[rr].x = fmaf(xu, a1[uu].x, acc1[rr].x);
            acc1[rr].y = fmaf(xu, a1[uu].y, acc1[rr].y);
            acc1[rr].z = fmaf(xu, a1[uu].z, acc1[rr].z);
            acc1[rr].w = fmaf(xu, a1[uu].w, acc1[rr].w);
            acc2[rr].x = fmaf(xu, a2[uu].x, acc2[rr].x);
            acc2[rr].y = fmaf(xu, a2[uu].y, acc2[rr].y);
            acc2[rr].z = fmaf(xu, a2[uu].z, acc2[rr].z);
            acc2[rr].w = fmaf(xu, a2[uu].w, acc2[rr].w);
          }
        }
      }
      if (L == 0){   // remainder k = 32 (cols 33..35 of x don't exist)
        float4 a1 = *(const float4*)&A  [(size_t)32*64 + o0];
        float4 a2 = *(const float4*)&Ahi[(size_t)32*64 + o0];
#pragma unroll
        for (int rr=0;rr<4;rr++){
          float xu = u.lay.xl[(r0+rr)*68 + 32];
          acc1[rr].x = fmaf(xu, a1.x, acc1[rr].x);
          acc1[rr].y = fmaf(xu, a1.y, acc1[rr].y);
          acc1[rr].z = fmaf(xu, a1.z, acc1[rr].z);
          acc1[rr].w = fmaf(xu, a1.w, acc1[rr].w);
          acc2[rr].x = fmaf(xu, a2.x, acc2[rr].x);
          acc2[rr].y = fmaf(xu, a2.y, acc2[rr].y);
          acc2[rr].z = fmaf(xu, a2.z, acc2[rr].z);
          acc2[rr].w = fmaf(xu, a2.w, acc2[rr].w);
        }
      }

      float4 alast = *(const float4*)&Alast[o0];
      float4 bo = *(const float4*)&bias[o0];
      float4 go = *(const float4*)&gam[o0];
      float4 be = *(const float4*)&bet[o0];
#pragma unroll
      for (int rr=0;rr<4;rr++){
        int r = rbase + jloc + r0 + rr;
        float sc = scl[r0+rr], tc = tcl[r0+rr], m = ml[r0+rr];
        float4 v;
        v.x = (acc1[rr].x + sc*acc2[rr].x + tc*alast.x + bo.x)*m;
        v.y = (acc1[rr].y + sc*acc2[rr].y + tc*alast.y + bo.y)*m;
        v.z = (acc1[rr].z + sc*acc2[rr].z + tc*alast.z + bo.z)*m;
        v.w = (acc1[rr].w + sc*acc2[rr].w + tc*alast.w + bo.w)*m;
        float4 tt;
        tt.x = tanhf(go.x*(v.x*INV_S) + be.x);
        tt.y = tanhf(go.y*(v.y*INV_S) + be.y);
        tt.z = tanhf(go.z*(v.z*INV_S) + be.z);
        tt.w = tanhf(go.w*(v.w*INV_S) + be.w);
        *(float4*)&xout[(size_t)r*64 + o0] = tt;
      }
    }
    __threadfence();
    grid.sync();
  }

  // ======================== dense0 split-K partial ========================
  // x5 lives in xA. X viewed as (64, 32768) row-major.
  {
    const float* X = a.xA;
    int og = (tid & 15)*8, rg = (tid >> 4)*4;
    for (int kb = bid; kb < 512; kb += gsz){
      int k0 = kb*64;
      float acc[4][8];
#pragma unroll
      for (int rr=0;rr<4;rr++)
#pragma unroll
        for (int uu=0;uu<8;uu++) acc[rr][uu]=0.f;
      for (int kt = 0; kt < 64; kt += 32){
        __syncthreads();
        for (int idx = tid; idx < 512; idx += 256){
          int r = idx >> 3, kq = idx & 7;
          *(float4*)&u.den.xt[r*36 + kq*4] =
              *(const float4*)&X[(size_t)r*32768 + k0 + kt + kq*4];
        }
        {
          const float4* Wc = (const float4*)&a.dW0[(size_t)(k0+kt)*128];
          float4* wt4 = (float4*)u.den.wt;
          for (int idx = tid; idx < 1024; idx += 256) wt4[idx] = Wc[idx];
        }
        __syncthreads();
#pragma unroll 4
        for (int k=0;k<32;k++){
          float4 w0 = *(const float4*)&u.den.wt[k*128 + og];
          float4 w1 = *(const float4*)&u.den.wt[k*128 + og + 4];
          float xs[4];
#pragma unroll
          for (int rr=0;rr<4;rr++) xs[rr] = u.den.xt[(rg+rr)*36 + k];
#pragma unroll
          for (int rr=0;rr<4;rr++){
            acc[rr][0] = fmaf(xs[rr], w0.x, acc[rr][0]);
            acc[rr][1] = fmaf(xs[rr], w0.y, acc[rr][1]);
            acc[rr][2] = fmaf(xs[rr], w0.z, acc[rr][2]);
            acc[rr][3] = fmaf(xs[rr], w0.w, acc[rr][3]);
            acc[rr][4] = fmaf(xs[rr], w1.x, acc[rr][4]);
            acc[rr][5] = fmaf(xs[rr], w1.y, acc[rr][5]);
            acc[rr][6] = fmaf(xs[rr], w1.z, acc[rr][6]);
            acc[rr][7] = fmaf(xs[rr], w1.w, acc[rr][7]);
          }
        }
      }
      float* pb = a.partial + (size_t)kb*8192;
#pragma unroll
      for (int rr=0;rr<4;rr++){
        *(float4*)&pb[(rg+rr)*128 + og]     = *(float4*)&acc[rr][0];
        *(float4*)&pb[(rg+rr)*128 + og + 4] = *(float4*)&acc[rr][4];
      }
    }
    __threadfence();
  }
  grid.sync();

  // ======================== head (blocks 0..63) ========================
  if (bid < 64){
    int bb = bid;
    int o = tid & 127, ph = tid >> 7;
    float s = 0.f;
#pragma unroll 16
    for (int p = ph*256; p < ph*256+256; p++)
      s += a.partial[(size_t)p*8192 + bb*128 + o];
    u.head.sred[tid] = s;
    __syncthreads();
    if (tid < 128){
      float sum = u.head.sred[tid] + u.head.sred[tid+128];
      float v = a.dbg[tid]*((sum + a.db0[tid])*INV_S) + a.dbb[tid];
      u.head.h[tid] = 1.f/(1.f + __expf(-v));
    }
    __syncthreads();
    if (tid < 128){
      float acc = 0.f;
#pragma unroll 8
      for (int k=0;k<128;k++) acc = fmaf(u.head.h[k], a.dW1[k*128 + tid], acc);
      float v = a.dbg[128+tid]*((acc + a.db1[tid])*INV_S) + a.dbb[128+tid];
      float h1 = 1.f/(1.f + __expf(-v));
      u.head.red0[tid] = h1 * a.W2[tid*2+0];
      u.head.red1[tid] = h1 * a.W2[tid*2+1];
    }
    __syncthreads();
    for (int st=64; st>0; st>>=1){
      if (tid < st){
        u.head.red0[tid] += u.head.red0[tid+st];
        u.head.red1[tid] += u.head.red1[tid+st];
      }
      __syncthreads();
    }
    if (tid == 0){
      a.out[bb*4+0] = u.head.red0[0] + a.b2[0];
      a.out[bb*4+1] = u.head.red1[0] + a.b2[1];
      a.out[bb*4+2] = 0.f;
      a.out[bb*4+3] = 0.f;
    }
  }
}

// ---------------------------------------------------------------------------
extern "C" void kernel_launch(void* const* d_in, const int* in_sizes, int n_in,
                              void* d_out, int out_size, void* d_ws, size_t ws_size,
                              hipStream_t stream)
{
  float* ws = (float*)d_ws;
  FusedArgs fa;
  fa.xx   = (const float*)d_in[0];
  fa.emb1 = (const float*)d_in[1];
  fa.emb2 = (const float*)d_in[2];
  fa.emb3 = (const float*)d_in[3];
  fa.A0   = (const float*)d_in[4];
  fa.b0   = (const float*)d_in[5];
  fa.Ar   = (const float*)d_in[6];
  fa.br   = (const float*)d_in[7];
  fa.bng  = (const float*)d_in[8];
  fa.bnb  = (const float*)d_in[9];
  fa.dW0  = (const float*)d_in[10];
  fa.db0  = (const float*)d_in[11];
  fa.dW1  = (const float*)d_in[12];
  fa.db1  = (const float*)d_in[13];
  fa.dbg  = (const float*)d_in[14];
  fa.dbb  = (const float*)d_in[15];
  fa.W2   = (const float*)d_in[16];
  fa.b2   = (const float*)d_in[17];
  fa.xA   = ws;                         // 32768*64
  fa.xB   = fa.xA + (size_t)R_*64;      // 32768*64
  fa.partial = fa.xB + (size_t)R_*64;   // 512*8192
  fa.out  = (float*)d_out;

  // Grid-size from the runtime's own occupancy calc (the cooperative
  // validator uses the same arithmetic, so this cannot be rejected).
  int occ = 0;
  hipError_t e = hipOccupancyMaxActiveBlocksPerMultiprocessor(
      &occ, (const void*)gnn_fused, 256, 0);
  if (e != hipSuccess || occ < 1) occ = 1;
  int g = occ * 256;
  if (g > 512) g = 512;
  if (g < 64)  g = 64;

  void* kargs[] = { &fa };
  hipLaunchCooperativeKernel((const void*)gnn_fused, dim3(g), dim3(256),
                             kargs, 0, stream);
}

// Round 7
// 242.019 us; speedup vs baseline: 3.8531x; 3.8531x over previous
//
#include <hip/hip_runtime.h>
#include <math.h>

#define B_ 64
#define N_ 512
#define R_ (B_*N_)                  // 32768 rows
#define INV_S 0.9995003746877732f   // 1/sqrt(1+1e-3)

// ---------------------------------------------------------------------------
// Fused GNN layer (multi-kernel structure — round 3 — with slim LDS).
// Block = (j-chunk of 64 rows) x (batch). LDS ~44 KB (was 61 KB -> 1
// block/CU): cl[512] coords 8 KB + A lo/hi 32 KB + reductions ~3 KB.
// Layers 1-4 read their x operands STRAIGHT from global in the k-loop
// (block-private 16 KB tile -> L1-resident; round 6 showed shared-A from
// global thrashes L2, so A stays in LDS, staged once per block).
// L0: small xl (64x36, 9 KB) built from xx + embeddings; K=33 pad 36.
// ---------------------------------------------------------------------------
template<int L0>
__global__ __launch_bounds__(256, 4) void gnn_layer(
    const float* __restrict__ xx, const float* __restrict__ xin,
    const float* __restrict__ A,
    const float* __restrict__ bias, const float* __restrict__ gamma,
    const float* __restrict__ beta,
    const float* __restrict__ emb1, const float* __restrict__ emb2,
    const float* __restrict__ emb3, float* __restrict__ xout)
{
  constexpr int KP = L0 ? 36 : 64;
  constexpr int K  = L0 ? 33 : 64;
  __shared__ float4 cl[512];
  __shared__ float alo[KP*64];
  __shared__ float ahi[KP*64];
  __shared__ float xl[L0 ? 64*36 : 4];
  __shared__ float spart[256], tpart[256];
  __shared__ float scl[64], tcl[64], ml[64];

  int tid = threadIdx.x;
  int jc = blockIdx.x;            // 0..7
  int b  = blockIdx.y;            // 0..63
  int rbase = b*N_, jloc = jc*64;

  // ---- stage coords (512 x float4) ----
  if constexpr (L0){
    for (int i = tid; i < 512; i += 256){
      const float* row = xx + (size_t)(rbase+i)*30;
      cl[i] = make_float4(row[25], row[26], 0.f, 0.f);
    }
  } else {
    for (int i = tid; i < 512; i += 256)
      cl[i] = *(const float4*)&xin[(size_t)(rbase+i)*64 + 60];
  }

  // ---- stage A lo/hi (zero-pad rows K..KP-1 for L0) ----
  if constexpr (L0){
    for (int idx = tid; idx < KP*64; idx += 256){
      int f = idx >> 6;
      alo[idx] = (f < K) ? A[idx] : 0.f;
      ahi[idx] = (f < K) ? A[(size_t)K*64 + idx] : 0.f;
    }
  } else {
    const float4* A4 = (const float4*)A;
    float4* alo4 = (float4*)alo;
    float4* ahi4 = (float4*)ahi;
    for (int idx = tid; idx < 1024; idx += 256){
      alo4[idx] = A4[idx];
      ahi4[idx] = A4[1024 + idx];
    }
  }

  // ---- L0: build x tile from xx + embeddings; mask ----
  if constexpr (L0){
    if (tid < 64){
      int r = rbase + jloc + tid;
      const float* row = xx + (size_t)r*30;
      float v[30];
#pragma unroll
      for (int i=0;i<30;i++) v[i] = row[i];
      int i1 = (int)fabsf(v[27]);
      int i2 = (int)fabsf(v[28]);
      int i3 = (int)fabsf(v[29]);
      float* o = &xl[tid*36];
      o[0]=emb1[i1*2+0]; o[1]=emb1[i1*2+1];
      o[2]=emb2[i2*2+0]; o[3]=emb2[i2*2+1];
      o[4]=emb3[i3*2+0]; o[5]=emb3[i3*2+1];
#pragma unroll
      for (int i=0;i<27;i++) o[6+i] = v[i];
      o[33]=0.f; o[34]=0.f; o[35]=0.f;
      ml[tid] = v[0];
    }
  } else {
    if (tid < 64) ml[tid] = xx[(size_t)(rbase+jloc+tid)*30];
  }
  __syncthreads();

  // ---- S,T: wave q sums i in [q*128, q*128+128) for j = tid&63 ----
  {
    int jj = tid & 63, q = tid >> 6;
    float4 cj = cl[jloc + jj];
    float Ss = 0.f, Ts = 0.f;
    int base = q*128;
#pragma unroll 8
    for (int i=0;i<128;i++){
      float4 ci = cl[base+i];
      float d0 = cj.x-ci.x, d1 = cj.y-ci.y, d2 = cj.z-ci.z, d3 = cj.w-ci.w;
      float dist = d0*d0 + d1*d1 + d2*d2 + d3*d3;
      float w = __expf(-10.f*dist);
      Ss += w;
      Ts += dist*w;
    }
    spart[tid] = Ss;
    tpart[tid] = Ts;
  }
  __syncthreads();
  if (tid < 64){
    float S = spart[tid] + spart[tid+64] + spart[tid+128] + spart[tid+192];
    float T = tpart[tid] + tpart[tid+64] + tpart[tid+128] + tpart[tid+192];
    float m = ml[tid];
    scl[tid] = m*S - 1.f;
    tcl[tid] = m*T;
  }
  __syncthreads();

  // ---- GEMM: thread = 4 rows x 4 outs, two matrices.
  //      A fragments from LDS; x from LDS (L0) or global (L>=1). ----
  int o0 = (tid & 15)*4, r0 = (tid >> 4)*4;
  const float* xb = xin + (size_t)(rbase + jloc + r0)*64;   // L>=1 only
  float4 acc1[4], acc2[4];
#pragma unroll
  for (int rr=0;rr<4;rr++){
    acc1[rr] = make_float4(0.f,0.f,0.f,0.f);
    acc2[rr] = make_float4(0.f,0.f,0.f,0.f);
  }
#pragma unroll 2
  for (int kc = 0; kc < KP; kc += 4){
    float4 a1[4], a2[4], xv[4];
#pragma unroll
    for (int uu=0;uu<4;uu++){
      a1[uu] = *(const float4*)&alo[(kc+uu)*64 + o0];
      a2[uu] = *(const float4*)&ahi[(kc+uu)*64 + o0];
    }
#pragma unroll
    for (int rr=0;rr<4;rr++){
      if constexpr (L0) xv[rr] = *(const float4*)&xl[(r0+rr)*36 + kc];
      else              xv[rr] = *(const float4*)&xb[rr*64 + kc];
    }
#pragma unroll
    for (int uu=0;uu<4;uu++){
#pragma unroll
      for (int rr=0;rr<4;rr++){
        float xu = ((const float*)&xv[rr])[uu];
        acc1[rr].x = fmaf(xu, a1[uu].x, acc1[rr].x);
        acc1[rr].y = fmaf(xu, a1[uu].y, acc1[rr].y);
        acc1[rr].z = fmaf(xu, a1[uu].z, acc1[rr].z);
        acc1[rr].w = fmaf(xu, a1[uu].w, acc1[rr].w);
        acc2[rr].x = fmaf(xu, a2[uu].x, acc2[rr].x);
        acc2[rr].y = fmaf(xu, a2[uu].y, acc2[rr].y);
        acc2[rr].z = fmaf(xu, a2[uu].z, acc2[rr].z);
        acc2[rr].w = fmaf(xu, a2[uu].w, acc2[rr].w);
      }
    }
  }

  float4 alast = *(const float4*)&A[(size_t)2*K*64 + o0];
  float4 bo = *(const float4*)&bias[o0];
  float4 go = *(const float4*)&gamma[o0];
  float4 be = *(const float4*)&beta[o0];
#pragma unroll
  for (int rr=0;rr<4;rr++){
    int r = rbase + jloc + r0 + rr;
    float sc = scl[r0+rr], tc = tcl[r0+rr], m = ml[r0+rr];
    float4 v;
    v.x = (acc1[rr].x + sc*acc2[rr].x + tc*alast.x + bo.x)*m;
    v.y = (acc1[rr].y + sc*acc2[rr].y + tc*alast.y + bo.y)*m;
    v.z = (acc1[rr].z + sc*acc2[rr].z + tc*alast.z + bo.z)*m;
    v.w = (acc1[rr].w + sc*acc2[rr].w + tc*alast.w + bo.w)*m;
    float4 t;
    t.x = tanhf(go.x*(v.x*INV_S) + be.x);
    t.y = tanhf(go.y*(v.y*INV_S) + be.y);
    t.z = tanhf(go.z*(v.z*INV_S) + be.z);
    t.w = tanhf(go.w*(v.w*INV_S) + be.w);
    *(float4*)&xout[(size_t)r*64 + o0] = t;
  }
}

// ---------------------------------------------------------------------------
// dense0 split-K partials. X viewed as (64, 32768) row-major. Block =
// k-chunk of 128, all 64 rows x 128 cols. Thread: 4 rows x 8 cols.
// ---------------------------------------------------------------------------
__global__ __launch_bounds__(256) void dense0_partial(
    const float* __restrict__ X, const float* __restrict__ W,
    float* __restrict__ partial)
{
  __shared__ float xt[64*32];
  __shared__ float wt[32*128];
  int tid = threadIdx.x;
  int k0 = blockIdx.x*128;
  int og = (tid & 15)*8;
  int rg = (tid >> 4)*4;
  float acc[4][8];
#pragma unroll
  for (int a=0;a<4;a++)
#pragma unroll
    for (int u=0;u<8;u++) acc[a][u]=0.f;
  for (int kt = 0; kt < 128; kt += 32){
    __syncthreads();
    for (int idx = tid; idx < 512; idx += 256){
      int r = idx >> 3, kq = idx & 7;
      *(float4*)&xt[r*32 + kq*4] =
          *(const float4*)&X[(size_t)r*32768 + k0 + kt + kq*4];
    }
    {
      const float4* Wc = (const float4*)&W[(size_t)(k0+kt)*128];
      float4* wt4 = (float4*)wt;
      for (int idx = tid; idx < 1024; idx += 256) wt4[idx] = Wc[idx];
    }
    __syncthreads();
#pragma unroll 4
    for (int k=0;k<32;k++){
      float4 w0 = *(const float4*)&wt[k*128 + og];
      float4 w1 = *(const float4*)&wt[k*128 + og + 4];
      float xs[4];
#pragma unroll
      for (int rr=0;rr<4;rr++) xs[rr] = xt[(rg+rr)*32 + k];
#pragma unroll
      for (int rr=0;rr<4;rr++){
        acc[rr][0] = fmaf(xs[rr], w0.x, acc[rr][0]);
        acc[rr][1] = fmaf(xs[rr], w0.y, acc[rr][1]);
        acc[rr][2] = fmaf(xs[rr], w0.z, acc[rr][2]);
        acc[rr][3] = fmaf(xs[rr], w0.w, acc[rr][3]);
        acc[rr][4] = fmaf(xs[rr], w1.x, acc[rr][4]);
        acc[rr][5] = fmaf(xs[rr], w1.y, acc[rr][5]);
        acc[rr][6] = fmaf(xs[rr], w1.z, acc[rr][6]);
        acc[rr][7] = fmaf(xs[rr], w1.w, acc[rr][7]);
      }
    }
  }
  float* pb = partial + (size_t)blockIdx.x*8192;
#pragma unroll
  for (int rr=0;rr<4;rr++){
    *(float4*)&pb[(rg+rr)*128 + og]     = *(float4*)&acc[rr][0];
    *(float4*)&pb[(rg+rr)*128 + og + 4] = *(float4*)&acc[rr][4];
  }
}

// ---------------------------------------------------------------------------
// Head: reduce 256 partials -> bn+sigmoid -> h; GEMV 128x128 -> bn+sigmoid
// -> @W2 + b2 -> out (B,4). One block per batch row.
// ---------------------------------------------------------------------------
__global__ __launch_bounds__(256) void dense_head(
    const float* __restrict__ partial,
    const float* __restrict__ db0, const float* __restrict__ dg0,
    const float* __restrict__ dbb0,
    const float* __restrict__ dW1, const float* __restrict__ db1,
    const float* __restrict__ dg1, const float* __restrict__ dbb1,
    const float* __restrict__ W2, const float* __restrict__ b2,
    float* __restrict__ out)
{
  __shared__ float sred[256];
  __shared__ float h[128];
  __shared__ float red0[128], red1[128];
  int tid = threadIdx.x;
  int b = blockIdx.x;
  int o = tid & 127, ph = tid >> 7;
  float s = 0.f;
#pragma unroll 16
  for (int p = ph*128; p < ph*128+128; p++)
    s += partial[(size_t)p*8192 + b*128 + o];
  sred[tid] = s;
  __syncthreads();
  if (tid < 128){
    float sum = sred[tid] + sred[tid+128];
    float v = dg0[tid]*((sum + db0[tid])*INV_S) + dbb0[tid];
    h[tid] = 1.f/(1.f + __expf(-v));
  }
  __syncthreads();
  if (tid < 128){
    float acc = 0.f;
#pragma unroll 8
    for (int k=0;k<128;k++) acc = fmaf(h[k], dW1[k*128 + tid], acc);
    float v = dg1[tid]*((acc + db1[tid])*INV_S) + dbb1[tid];
    float h1 = 1.f/(1.f + __expf(-v));
    red0[tid] = h1 * W2[tid*2+0];
    red1[tid] = h1 * W2[tid*2+1];
  }
  __syncthreads();
  for (int st=64; st>0; st>>=1){
    if (tid < st){ red0[tid] += red0[tid+st]; red1[tid] += red1[tid+st]; }
    __syncthreads();
  }
  if (tid == 0){
    out[b*4+0] = red0[0] + b2[0];
    out[b*4+1] = red1[0] + b2[1];
    out[b*4+2] = 0.f;
    out[b*4+3] = 0.f;
  }
}

// ---------------------------------------------------------------------------
extern "C" void kernel_launch(void* const* d_in, const int* in_sizes, int n_in,
                              void* d_out, int out_size, void* d_ws, size_t ws_size,
                              hipStream_t stream)
{
  const float* xx   = (const float*)d_in[0];
  const float* emb1 = (const float*)d_in[1];
  const float* emb2 = (const float*)d_in[2];
  const float* emb3 = (const float*)d_in[3];
  const float* A0   = (const float*)d_in[4];
  const float* b0   = (const float*)d_in[5];
  const float* Ar   = (const float*)d_in[6];   // (4,129,64)
  const float* br   = (const float*)d_in[7];   // (4,64)
  const float* bng  = (const float*)d_in[8];   // (5,64)
  const float* bnb  = (const float*)d_in[9];   // (5,64)
  const float* dW0  = (const float*)d_in[10];  // (32768,128)
  const float* db0  = (const float*)d_in[11];
  const float* dW1  = (const float*)d_in[12];  // (128,128)
  const float* db1  = (const float*)d_in[13];
  const float* dbg  = (const float*)d_in[14];  // (2,128)
  const float* dbb  = (const float*)d_in[15];
  const float* W2   = (const float*)d_in[16];  // (128,2)
  const float* b2   = (const float*)d_in[17];

  float* ws = (float*)d_ws;
  float* xA      = ws;                               // 32768*64
  float* xB      = xA + (size_t)R_*64;               // 32768*64
  float* partial = xB + (size_t)R_*64;               // 256*8192

  dim3 lgrid(8, 64);
  // layer 0 -> xA
  gnn_layer<1><<<lgrid, 256, 0, stream>>>(
      xx, nullptr, A0, b0, bng, bnb, emb1, emb2, emb3, xA);
  // layers 1..4 ping-pong; x5 ends in xA
  float* bufs[2] = {xA, xB};
  int curi = 0;
  for (int k=0;k<4;k++){
    const float* cur = bufs[curi];
    float* nxt = bufs[1-curi];
    gnn_layer<0><<<lgrid, 256, 0, stream>>>(
        xx, cur, Ar + (size_t)k*129*64, br + k*64,
        bng + (k+1)*64, bnb + (k+1)*64, emb1, emb2, emb3, nxt);
    curi ^= 1;
  }
  const float* x5 = bufs[curi];   // xA

  dense0_partial<<<256, 256, 0, stream>>>(x5, dW0, partial);
  dense_head<<<B_, 256, 0, stream>>>(partial, db0, dbg, dbb,
                                     dW1, db1, dbg + 128, dbb + 128,
                                     W2, b2, (float*)d_out);
}

// Round 8
// 219.373 us; speedup vs baseline: 4.2508x; 1.1032x over previous
//
#include <hip/hip_runtime.h>
#include <math.h>

#define B_ 64
#define N_ 512
#define R_ (B_*N_)                  // 32768 rows
#define INV_S 0.9995003746877732f   // 1/sqrt(1+1e-3)

__device__ __forceinline__ float fast_tanh(float y){
  // tanh(y) = 1 - 2/(1 + e^{2y}); v_exp + v_rcp, ~6 VALU vs ~30 for tanhf
  return 1.f - 2.f*__builtin_amdgcn_rcpf(1.f + __expf(2.f*y));
}
__device__ __forceinline__ float fast_sigmoid(float v){
  return __builtin_amdgcn_rcpf(1.f + __expf(-v));
}

// ---------------------------------------------------------------------------
// Fused GNN layer. Block = (j-chunk of 64 rows) x (batch).
// Coords for S/T are staged from a COMPACT float4 buffer written by the
// previous layer's epilogue (round 7 read them at stride 256B from xout,
// 8x duplicated per batch -> scattered 16B loads). Mask likewise from a
// compact buffer written by L0. A lo/hi staged in LDS (round 6 showed
// global-A thrashes L2). x operand: LDS tile for L0 (built from xx +
// embeddings), straight-from-global (L1-resident) for L>=1.
// ---------------------------------------------------------------------------
template<int L0>
__global__ __launch_bounds__(256, 4) void gnn_layer(
    const float* __restrict__ xx, const float* __restrict__ xin,
    const float4* __restrict__ cin, const float* __restrict__ A,
    const float* __restrict__ bias, const float* __restrict__ gamma,
    const float* __restrict__ beta,
    const float* __restrict__ emb1, const float* __restrict__ emb2,
    const float* __restrict__ emb3,
    const float* __restrict__ maskb,     // compact mask (L>=1)
    float* __restrict__ maskout,         // compact mask out (L0 only)
    float4* __restrict__ cout,           // compact coords out (null for L4)
    float* __restrict__ xout)
{
  constexpr int KP = L0 ? 36 : 64;
  constexpr int K  = L0 ? 33 : 64;
  __shared__ float4 cl[512];
  __shared__ float alo[KP*64];
  __shared__ float ahi[KP*64];
  __shared__ float xl[L0 ? 64*36 : 4];
  __shared__ float spart[256], tpart[256];
  __shared__ float scl[64], tcl[64], ml[64];

  int tid = threadIdx.x;
  int jc = blockIdx.x;            // 0..7
  int b  = blockIdx.y;            // 0..63
  int rbase = b*N_, jloc = jc*64;

  // ---- stage coords (512 x float4) ----
  if constexpr (L0){
    for (int i = tid; i < 512; i += 256){
      const float* row = xx + (size_t)(rbase+i)*30;
      cl[i] = make_float4(row[25], row[26], 0.f, 0.f);
    }
  } else {
    for (int i = tid; i < 512; i += 256)
      cl[i] = cin[rbase + i];                       // coalesced 16B/lane
  }

  // ---- stage A lo/hi ----
  if constexpr (L0){
    for (int idx = tid; idx < KP*64; idx += 256){
      int f = idx >> 6;
      alo[idx] = (f < K) ? A[idx] : 0.f;
      ahi[idx] = (f < K) ? A[(size_t)K*64 + idx] : 0.f;
    }
  } else {
    const float4* A4 = (const float4*)A;
    float4* alo4 = (float4*)alo;
    float4* ahi4 = (float4*)ahi;
    for (int idx = tid; idx < 1024; idx += 256){
      alo4[idx] = A4[idx];
      ahi4[idx] = A4[1024 + idx];
    }
  }

  // ---- L0: build x tile + mask; L>=1: compact mask load ----
  if constexpr (L0){
    if (tid < 64){
      int r = rbase + jloc + tid;
      const float* row = xx + (size_t)r*30;
      float v[30];
#pragma unroll
      for (int i=0;i<30;i++) v[i] = row[i];
      int i1 = (int)fabsf(v[27]);
      int i2 = (int)fabsf(v[28]);
      int i3 = (int)fabsf(v[29]);
      float* o = &xl[tid*36];
      o[0]=emb1[i1*2+0]; o[1]=emb1[i1*2+1];
      o[2]=emb2[i2*2+0]; o[3]=emb2[i2*2+1];
      o[4]=emb3[i3*2+0]; o[5]=emb3[i3*2+1];
#pragma unroll
      for (int i=0;i<27;i++) o[6+i] = v[i];
      o[33]=0.f; o[34]=0.f; o[35]=0.f;
      ml[tid] = v[0];
      maskout[r] = v[0];
    }
  } else {
    if (tid < 64) ml[tid] = maskb[rbase + jloc + tid];
  }
  __syncthreads();

  // ---- S,T: wave q sums i in [q*128, q*128+128) for j = tid&63 ----
  {
    int jj = tid & 63, q = tid >> 6;
    float4 cj = cl[jloc + jj];
    float Ss = 0.f, Ts = 0.f;
    int base = q*128;
#pragma unroll 8
    for (int i=0;i<128;i++){
      float4 ci = cl[base+i];
      float d0 = cj.x-ci.x, d1 = cj.y-ci.y, d2 = cj.z-ci.z, d3 = cj.w-ci.w;
      float dist = d0*d0 + d1*d1 + d2*d2 + d3*d3;
      float w = __expf(-10.f*dist);
      Ss += w;
      Ts += dist*w;
    }
    spart[tid] = Ss;
    tpart[tid] = Ts;
  }
  __syncthreads();
  if (tid < 64){
    float S = spart[tid] + spart[tid+64] + spart[tid+128] + spart[tid+192];
    float T = tpart[tid] + tpart[tid+64] + tpart[tid+128] + tpart[tid+192];
    float m = ml[tid];
    scl[tid] = m*S - 1.f;
    tcl[tid] = m*T;
  }
  __syncthreads();

  // ---- GEMM: thread = 4 rows x 4 outs, two matrices ----
  int o0 = (tid & 15)*4, r0 = (tid >> 4)*4;
  const float* xb = xin + (size_t)(rbase + jloc + r0)*64;   // L>=1 only
  float4 acc1[4], acc2[4];
#pragma unroll
  for (int rr=0;rr<4;rr++){
    acc1[rr] = make_float4(0.f,0.f,0.f,0.f);
    acc2[rr] = make_float4(0.f,0.f,0.f,0.f);
  }
#pragma unroll 2
  for (int kc = 0; kc < KP; kc += 4){
    float4 a1[4], a2[4], xv[4];
#pragma unroll
    for (int uu=0;uu<4;uu++){
      a1[uu] = *(const float4*)&alo[(kc+uu)*64 + o0];
      a2[uu] = *(const float4*)&ahi[(kc+uu)*64 + o0];
    }
#pragma unroll
    for (int rr=0;rr<4;rr++){
      if constexpr (L0) xv[rr] = *(const float4*)&xl[(r0+rr)*36 + kc];
      else              xv[rr] = *(const float4*)&xb[rr*64 + kc];
    }
#pragma unroll
    for (int uu=0;uu<4;uu++){
#pragma unroll
      for (int rr=0;rr<4;rr++){
        float xu = ((const float*)&xv[rr])[uu];
        acc1[rr].x = fmaf(xu, a1[uu].x, acc1[rr].x);
        acc1[rr].y = fmaf(xu, a1[uu].y, acc1[rr].y);
        acc1[rr].z = fmaf(xu, a1[uu].z, acc1[rr].z);
        acc1[rr].w = fmaf(xu, a1[uu].w, acc1[rr].w);
        acc2[rr].x = fmaf(xu, a2[uu].x, acc2[rr].x);
        acc2[rr].y = fmaf(xu, a2[uu].y, acc2[rr].y);
        acc2[rr].z = fmaf(xu, a2[uu].z, acc2[rr].z);
        acc2[rr].w = fmaf(xu, a2[uu].w, acc2[rr].w);
      }
    }
  }

  float4 alast = *(const float4*)&A[(size_t)2*K*64 + o0];
  float4 bo = *(const float4*)&bias[o0];
  float4 go = *(const float4*)&gamma[o0];
  float4 be = *(const float4*)&beta[o0];
#pragma unroll
  for (int rr=0;rr<4;rr++){
    int r = rbase + jloc + r0 + rr;
    float sc = scl[r0+rr], tc = tcl[r0+rr], m = ml[r0+rr];
    float4 v;
    v.x = (acc1[rr].x + sc*acc2[rr].x + tc*alast.x + bo.x)*m;
    v.y = (acc1[rr].y + sc*acc2[rr].y + tc*alast.y + bo.y)*m;
    v.z = (acc1[rr].z + sc*acc2[rr].z + tc*alast.z + bo.z)*m;
    v.w = (acc1[rr].w + sc*acc2[rr].w + tc*alast.w + bo.w)*m;
    float4 t;
    t.x = fast_tanh(go.x*(v.x*INV_S) + be.x);
    t.y = fast_tanh(go.y*(v.y*INV_S) + be.y);
    t.z = fast_tanh(go.z*(v.z*INV_S) + be.z);
    t.w = fast_tanh(go.w*(v.w*INV_S) + be.w);
    *(float4*)&xout[(size_t)r*64 + o0] = t;
    if (cout && o0 == 60) cout[r] = t;   // compact coords for next layer
  }
}

// ---------------------------------------------------------------------------
// dense0 split-K partials. X viewed as (64, 32768) row-major. Block =
// k-chunk of 128, all 64 rows x 128 cols. Thread: 4 rows x 8 cols.
// ---------------------------------------------------------------------------
__global__ __launch_bounds__(256) void dense0_partial(
    const float* __restrict__ X, const float* __restrict__ W,
    float* __restrict__ partial)
{
  __shared__ float xt[64*32];
  __shared__ float wt[32*128];
  int tid = threadIdx.x;
  int k0 = blockIdx.x*128;
  int og = (tid & 15)*8;
  int rg = (tid >> 4)*4;
  float acc[4][8];
#pragma unroll
  for (int a=0;a<4;a++)
#pragma unroll
    for (int u=0;u<8;u++) acc[a][u]=0.f;
  for (int kt = 0; kt < 128; kt += 32){
    __syncthreads();
    for (int idx = tid; idx < 512; idx += 256){
      int r = idx >> 3, kq = idx & 7;
      *(float4*)&xt[r*32 + kq*4] =
          *(const float4*)&X[(size_t)r*32768 + k0 + kt + kq*4];
    }
    {
      const float4* Wc = (const float4*)&W[(size_t)(k0+kt)*128];
      float4* wt4 = (float4*)wt;
      for (int idx = tid; idx < 1024; idx += 256) wt4[idx] = Wc[idx];
    }
    __syncthreads();
#pragma unroll 4
    for (int k=0;k<32;k++){
      float4 w0 = *(const float4*)&wt[k*128 + og];
      float4 w1 = *(const float4*)&wt[k*128 + og + 4];
      float xs[4];
#pragma unroll
      for (int rr=0;rr<4;rr++) xs[rr] = xt[(rg+rr)*32 + k];
#pragma unroll
      for (int rr=0;rr<4;rr++){
        acc[rr][0] = fmaf(xs[rr], w0.x, acc[rr][0]);
        acc[rr][1] = fmaf(xs[rr], w0.y, acc[rr][1]);
        acc[rr][2] = fmaf(xs[rr], w0.z, acc[rr][2]);
        acc[rr][3] = fmaf(xs[rr], w0.w, acc[rr][3]);
        acc[rr][4] = fmaf(xs[rr], w1.x, acc[rr][4]);
        acc[rr][5] = fmaf(xs[rr], w1.y, acc[rr][5]);
        acc[rr][6] = fmaf(xs[rr], w1.z, acc[rr][6]);
        acc[rr][7] = fmaf(xs[rr], w1.w, acc[rr][7]);
      }
    }
  }
  float* pb = partial + (size_t)blockIdx.x*8192;
#pragma unroll
  for (int rr=0;rr<4;rr++){
    *(float4*)&pb[(rg+rr)*128 + og]     = *(float4*)&acc[rr][0];
    *(float4*)&pb[(rg+rr)*128 + og + 4] = *(float4*)&acc[rr][4];
  }
}

// ---------------------------------------------------------------------------
// Head: reduce 256 partials -> bn+sigmoid -> h; GEMV 128x128 -> bn+sigmoid
// -> @W2 + b2 -> out (B,4). One block per batch row.
// ---------------------------------------------------------------------------
__global__ __launch_bounds__(256) void dense_head(
    const float* __restrict__ partial,
    const float* __restrict__ db0, const float* __restrict__ dg0,
    const float* __restrict__ dbb0,
    const float* __restrict__ dW1, const float* __restrict__ db1,
    const float* __restrict__ dg1, const float* __restrict__ dbb1,
    const float* __restrict__ W2, const float* __restrict__ b2,
    float* __restrict__ out)
{
  __shared__ float sred[256];
  __shared__ float h[128];
  __shared__ float red0[128], red1[128];
  int tid = threadIdx.x;
  int b = blockIdx.x;
  int o = tid & 127, ph = tid >> 7;
  float s = 0.f;
#pragma unroll 16
  for (int p = ph*128; p < ph*128+128; p++)
    s += partial[(size_t)p*8192 + b*128 + o];
  sred[tid] = s;
  __syncthreads();
  if (tid < 128){
    float sum = sred[tid] + sred[tid+128];
    float v = dg0[tid]*((sum + db0[tid])*INV_S) + dbb0[tid];
    h[tid] = fast_sigmoid(v);
  }
  __syncthreads();
  if (tid < 128){
    float acc = 0.f;
#pragma unroll 8
    for (int k=0;k<128;k++) acc = fmaf(h[k], dW1[k*128 + tid], acc);
    float v = dg1[tid]*((acc + db1[tid])*INV_S) + dbb1[tid];
    float h1 = fast_sigmoid(v);
    red0[tid] = h1 * W2[tid*2+0];
    red1[tid] = h1 * W2[tid*2+1];
  }
  __syncthreads();
  for (int st=64; st>0; st>>=1){
    if (tid < st){ red0[tid] += red0[tid+st]; red1[tid] += red1[tid+st]; }
    __syncthreads();
  }
  if (tid == 0){
    out[b*4+0] = red0[0] + b2[0];
    out[b*4+1] = red1[0] + b2[1];
    out[b*4+2] = 0.f;
    out[b*4+3] = 0.f;
  }
}

// ---------------------------------------------------------------------------
extern "C" void kernel_launch(void* const* d_in, const int* in_sizes, int n_in,
                              void* d_out, int out_size, void* d_ws, size_t ws_size,
                              hipStream_t stream)
{
  const float* xx   = (const float*)d_in[0];
  const float* emb1 = (const float*)d_in[1];
  const float* emb2 = (const float*)d_in[2];
  const float* emb3 = (const float*)d_in[3];
  const float* A0   = (const float*)d_in[4];
  const float* b0   = (const float*)d_in[5];
  const float* Ar   = (const float*)d_in[6];   // (4,129,64)
  const float* br   = (const float*)d_in[7];   // (4,64)
  const float* bng  = (const float*)d_in[8];   // (5,64)
  const float* bnb  = (const float*)d_in[9];   // (5,64)
  const float* dW0  = (const float*)d_in[10];  // (32768,128)
  const float* db0  = (const float*)d_in[11];
  const float* dW1  = (const float*)d_in[12];  // (128,128)
  const float* db1  = (const float*)d_in[13];
  const float* dbg  = (const float*)d_in[14];  // (2,128)
  const float* dbb  = (const float*)d_in[15];
  const float* W2   = (const float*)d_in[16];  // (128,2)
  const float* b2   = (const float*)d_in[17];

  float* ws = (float*)d_ws;
  float* xA      = ws;                               // 32768*64
  float* xB      = xA + (size_t)R_*64;               // 32768*64
  float* partial = xB + (size_t)R_*64;               // 256*8192
  float* maskb   = partial + (size_t)256*8192;       // 32768
  float4* cbuf   = (float4*)(maskb + R_);            // 32768 float4

  dim3 lgrid(8, 64);
  // layer 0 -> xA (+ compact mask + compact coords)
  gnn_layer<1><<<lgrid, 256, 0, stream>>>(
      xx, nullptr, nullptr, A0, b0, bng, bnb, emb1, emb2, emb3,
      nullptr, maskb, cbuf, xA);
  // layers 1..4 ping-pong; x5 ends in xA
  float* bufs[2] = {xA, xB};
  int curi = 0;
  for (int k=0;k<4;k++){
    const float* cur = bufs[curi];
    float* nxt = bufs[1-curi];
    gnn_layer<0><<<lgrid, 256, 0, stream>>>(
        xx, cur, cbuf, Ar + (size_t)k*129*64, br + k*64,
        bng + (k+1)*64, bnb + (k+1)*64, emb1, emb2, emb3,
        maskb, nullptr, (k < 3) ? cbuf : nullptr, nxt);
    curi ^= 1;
  }
  const float* x5 = bufs[curi];   // xA

  dense0_partial<<<256, 256, 0, stream>>>(x5, dW0, partial);
  dense_head<<<B_, 256, 0, stream>>>(partial, db0, dbg, dbb,
                                     dW1, db1, dbg + 128, dbb + 128,
                                     W2, b2, (float*)d_out);
}